// Round 20
// baseline (156.772 us; speedup 1.0000x reference)
//
#include <hip/hip_runtime.h>
#include <hip/hip_bf16.h>

typedef __bf16 bf16_t;
typedef __attribute__((ext_vector_type(8))) __bf16 bf16x8;
typedef __attribute__((ext_vector_type(4))) float f32x4;
typedef __attribute__((ext_vector_type(8))) int i32x8;
typedef __attribute__((ext_vector_type(4))) int i32x4;

#define NEGV (-1e30f)

// Problem constants
#define BB 4
#define TT 200
#define UU 50
#define U1 51
#define VV 1024
#define DD 512
#define HH 640
#define RTOT (BB*TT*U1)      // 40800
#define NBLK 638
#define SS 101

__device__ __forceinline__ float lae(float a, float b) {
    float mx = fmaxf(a, b);
    return mx + __logf(__expf(a - mx) + __expf(b - mx));
}
__device__ __forceinline__ float lae3(float a, float b, float c) {
    float mx = fmaxf(fmaxf(a, b), c);
    return mx + __logf(__expf(a - mx) + __expf(b - mx) + __expf(c - mx));
}
// cheap tanh for the fp8 build: exp + hw-rcp (1ulp, irrelevant at fp8)
__device__ __forceinline__ float tanh_rcp(float x) {
    x = fminf(fmaxf(x, -10.f), 10.f);
    float ex = __expf(2.f * x);
    float r = __builtin_amdgcn_rcpf(ex + 1.f);
    return (ex - 1.f) * r;
}

// ---------------- pack fp32 (K x N) weight into bf16 MFMA B-fragment order.
__device__ __forceinline__ void pack_seg(const float* __restrict__ W, bf16_t* __restrict__ Wf,
                                         int e, int K32, int N)
{
    int j  = e & 7;
    int l  = (e >> 3) & 63;
    int kk = (e >> 9) % K32;
    int nt = e / (K32 * 512);
    int v = nt * 16 + (l & 15);
    int k = kk * 32 + ((l >> 4) << 2) + (j & 3) + ((j >> 2) << 4);
    Wf[e] = (bf16_t)W[(size_t)k * N + v];
}

// ---- pack W_out into fp8 e4m3 (scaled x16) for the MX K=128 MFMA.
// Layout: [nt(64)][ks(5)][l(64)][32B]; byte m of lane l holds
// k = ks*128 + (l>>4)*32 + m, col v = nt*16 + (l&15).  (A shares k-map.)
__device__ __forceinline__ void pack_out8_mx(const float* __restrict__ W, unsigned* __restrict__ Wf8,
                                             int e32)
{
    int w4   = e32 & 7;          // word within 32B
    int l    = (e32 >> 3) & 63;
    int ksnt = e32 >> 9;
    int ks   = ksnt % 5;
    int nt   = ksnt / 5;
    int v = nt * 16 + (l & 15);
    int kb = ks * 128 + ((l >> 4) << 5) + w4 * 4;
    float f[4];
#pragma unroll
    for (int t = 0; t < 4; ++t) f[t] = W[(size_t)(kb + t) * VV + v] * 16.f;
    unsigned r = __builtin_amdgcn_cvt_pk_fp8_f32(f[0], f[1], 0, false);
    r = __builtin_amdgcn_cvt_pk_fp8_f32(f[2], f[3], r, true);
    Wf8[e32] = r;
}

// bf16 packs only (FOut8 rides in the gemm3 launch); also zeroes out[0]
__global__ void pack_bf16(const float* __restrict__ Wenc, const float* __restrict__ Wpred,
                          const float* __restrict__ Wctc,
                          bf16_t* __restrict__ FEnc, bf16_t* __restrict__ FPred,
                          bf16_t* __restrict__ FCtc, float* __restrict__ out)
{
    if (blockIdx.x == 0 && threadIdx.x == 0) out[0] = 0.f;
    int e = blockIdx.x * 256 + threadIdx.x;
    if (e < 327680) { pack_seg(Wenc, FEnc, e, 16, 640); return; }
    e -= 327680;
    if (e < 409600) { pack_seg(Wpred, FPred, e, 20, 640); return; }
    e -= 409600;
    pack_seg(Wctc, FCtc, e, 16, 1024);
}

// ---------------- generic bf16 MFMA GEMM (small gemms) ---------------------
template<int K32, int L, bool LSE, int J>
__device__ void gemm_dev(const float* __restrict__ A, int M, int rowbase, int K,
                         const bf16_t* __restrict__ Wf, const float* __restrict__ bias,
                         float* __restrict__ C, float* __restrict__ lse_out, int N,
                         bf16_t* Atile, float (*ps)[8])
{
    const int tid = threadIdx.x;
#pragma unroll
    for (int it = 0; it < J * K32 / 8; ++it) {
        int fi = it * 512 + tid;
        int l = fi & 63, jk = fi >> 6;
        int j = jk / K32, kk = jk - j * K32;
        int row = rowbase + j * 16 + (l & 15);
        if (row > M - 1) row = M - 1;
        int c0 = kk * 32 + ((l >> 4) << 2);
        const float4 a0 = *(const float4*)&A[(size_t)row * K + c0];
        const float4 a1 = *(const float4*)&A[(size_t)row * K + c0 + 16];
        bf16x8 v;
        v[0] = (bf16_t)a0.x; v[1] = (bf16_t)a0.y; v[2] = (bf16_t)a0.z; v[3] = (bf16_t)a0.w;
        v[4] = (bf16_t)a1.x; v[5] = (bf16_t)a1.y; v[6] = (bf16_t)a1.z; v[7] = (bf16_t)a1.w;
        *(bf16x8*)&Atile[(size_t)fi * 8] = v;
    }
    __syncthreads();

    const int l = tid & 63, w = tid >> 6;
    const int lrow = l & 15, lhi = l >> 4;

    f32x4 acc[J][L];
#pragma unroll
    for (int j = 0; j < J; ++j)
#pragma unroll
        for (int li = 0; li < L; ++li) acc[j][li] = f32x4{0.f, 0.f, 0.f, 0.f};

    for (int kk = 0; kk < K32; ++kk) {
        bf16x8 a[J];
#pragma unroll
        for (int j = 0; j < J; ++j)
            a[j] = *(const bf16x8*)&Atile[(size_t)(((j * K32 + kk) * 64 + l) * 8)];
#pragma unroll
        for (int li = 0; li < L; ++li) {
            bf16x8 b = *(const bf16x8*)&Wf[(size_t)(((w * L + li) * K32 + kk) * 64 + l) * 8];
#pragma unroll
            for (int j = 0; j < J; ++j)
                acc[j][li] = __builtin_amdgcn_mfma_f32_16x16x32_bf16(a[j], b, acc[j][li], 0, 0, 0);
        }
    }

    float se[J][4];
    if (LSE) {
#pragma unroll
        for (int j = 0; j < J; ++j)
#pragma unroll
            for (int i = 0; i < 4; ++i) se[j][i] = 0.f;
    }
#pragma unroll
    for (int j = 0; j < J; ++j)
#pragma unroll
        for (int li = 0; li < L; ++li) {
            int col = (w * L + li) * 16 + lrow;
            float bv = bias ? bias[col] : 0.f;
#pragma unroll
            for (int i = 0; i < 4; ++i) {
                int grow = rowbase + 16 * j + lhi * 4 + i;
                float x = acc[j][li][i] + bv;
                if (grow < M) C[(size_t)grow * N + col] = x;
                if (LSE) se[j][i] += __expf(x);
            }
        }
    if (LSE) {
#pragma unroll
        for (int d = 1; d < 16; d <<= 1)
#pragma unroll
            for (int j = 0; j < J; ++j)
#pragma unroll
                for (int i = 0; i < 4; ++i) se[j][i] += __shfl_xor(se[j][i], d);
        if (lrow == 0) {
#pragma unroll
            for (int j = 0; j < J; ++j)
#pragma unroll
                for (int i = 0; i < 4; ++i) ps[16 * j + lhi * 4 + i][w] = se[j][i];
        }
        __syncthreads();
        if (tid < J * 16) {
            float s = 0.f;
#pragma unroll
            for (int w0 = 0; w0 < 8; ++w0) s += ps[tid][w0];
            int grow = rowbase + tid;
            if (grow < M) lse_out[grow] = __logf(s);
        }
    }
}

// blocks 0..49 enc(J=1), 50..56 pred(J=2), 57..106 ctc(J=1),
// 107..426: pack W_out -> fp8 (concurrent on the idle CUs).
__global__ __launch_bounds__(512)
void mfma_gemm3(const float* __restrict__ x_enc, const float* __restrict__ x_dec,
                const bf16_t* __restrict__ FEnc, const bf16_t* __restrict__ FPred,
                const bf16_t* __restrict__ FCtc, const float* __restrict__ b_ctc,
                float* __restrict__ enc_proj, float* __restrict__ pred_proj,
                float* __restrict__ ctc_logits, float* __restrict__ ctc_lse,
                const float* __restrict__ Wout, unsigned* __restrict__ FOut8)
{
    __shared__ bf16_t Atile[2560 * 8];   // J=2,K32=20 max: 2560 frags
    __shared__ float ps[64][8];
    int blk = blockIdx.x;
    if (blk >= 107) {
        int e = (blk - 107) * 512 + threadIdx.x;   // 163840 u32 total
        pack_out8_mx(Wout, FOut8, e);
        return;
    }
    if (blk < 50)
        gemm_dev<16, 5, false, 1>(x_enc, 800, blk * 16, 512, FEnc, nullptr, enc_proj, nullptr, 640, Atile, ps);
    else if (blk < 57)
        gemm_dev<20, 5, false, 2>(x_dec, 204, (blk - 50) * 32, 640, FPred, nullptr, pred_proj, nullptr, 640, Atile, ps);
    else
        gemm_dev<16, 8, true, 1>(x_enc, 800, (blk - 57) * 16, 512, FCtc, b_ctc, ctc_logits, ctc_lse, 1024, Atile, ps);
}

// ---------------- fused build + MX-fp8 K=128 GEMM + row-LSE + gather -------
// Build in-place in LDS: P1 row-major coalesced tanh->fp8 tile [64][656B];
// P2 each thread lifts its 5 fragment chunks to regs, barrier, writes them
// back fragment-ordered (Afrag layout [j][ks][half][l][16B]) into the SAME
// buffer. Then the R18 K-loop/epilogue unchanged.
__global__ __launch_bounds__(512)
void joint_gemm(const float* __restrict__ enc,   // (800,640)
                const float* __restrict__ pred,  // (204,640)
                const float* __restrict__ bj,    // (640)
                const unsigned* __restrict__ Wf8,// packed fp8 (x16 scale)
                const float* __restrict__ bo,    // (1024)
                const int* __restrict__ target,  // (4,50)
                float* __restrict__ blank_buf, float* __restrict__ emit_buf)
{
    __shared__ __align__(16) char smbuf[43008];   // P1 tile 41984 / Afrag 40960
    __shared__ const float* ep[64];
    __shared__ const float* pp[64];
    char* Afrag8 = smbuf;
    const int tid = threadIdx.x;
    const int blk = blockIdx.x;

    const int l = tid & 63, w = tid >> 6;
    const int lrow = l & 15, lhi = l >> 4;

    if (tid < 64) {
        int r = blk * 64 + tid; if (r > RTOT - 1) r = RTOT - 1;
        int b = r / (TT * U1); int rem = r - b * (TT * U1);
        int t = rem / U1;      int u = rem - t * U1;
        ep[tid] = enc + (size_t)(b * TT + t) * HH;
        pp[tid] = pred + (size_t)(b * U1 + u) * HH;
    }
    __syncthreads();

    // P1: row-major coalesced compute -> LDS fp8 tile [64][656B]
#pragma unroll 4
    for (int it = 0; it < 20; ++it) {
        int i = it * 512 + tid;        // 0..10239
        int row = i / 160;
        int c4 = i - row * 160;
        int c0 = c4 * 4;
        const float4 e4 = *(const float4*)&ep[row][c0];
        const float4 p4 = *(const float4*)&pp[row][c0];
        const float4 q4 = *(const float4*)&bj[c0];
        float f0 = tanh_rcp(e4.x + p4.x + q4.x);
        float f1 = tanh_rcp(e4.y + p4.y + q4.y);
        float f2 = tanh_rcp(e4.z + p4.z + q4.z);
        float f3 = tanh_rcp(e4.w + p4.w + q4.w);
        unsigned r0 = __builtin_amdgcn_cvt_pk_fp8_f32(f0, f1, 0, false);
        unsigned v = __builtin_amdgcn_cvt_pk_fp8_f32(f2, f3, r0, true);
        *(unsigned*)&smbuf[row * 656 + c0] = v;
    }
    __syncthreads();

    // P2: in-place permute row-major -> fragment order (regs + barrier).
    uint4 frag[5];
    int cdst[5];
#pragma unroll
    for (int it = 0; it < 5; ++it) {
        int c = it * 512 + tid;        // 0..2559
        int lA = c & 63;
        int plane = c >> 6;            // 0..39
        int h = plane & 1;
        int jks = plane >> 1;
        int ks = jks % 5;
        int j = jks / 5;
        int row = j * 16 + (lA & 15);
        int kbase = ks * 128 + ((lA >> 4) << 5) + h * 16;
        frag[it] = *(const uint4*)&smbuf[row * 656 + kbase];
        cdst[it] = c;
    }
    __syncthreads();
#pragma unroll
    for (int it = 0; it < 5; ++it)
        *(uint4*)&Afrag8[(size_t)cdst[it] * 16] = frag[it];
    __syncthreads();

    f32x4 acc[4][8];
#pragma unroll
    for (int j = 0; j < 4; ++j)
#pragma unroll
        for (int li = 0; li < 8; ++li) acc[j][li] = f32x4{0.f, 0.f, 0.f, 0.f};

    const char* Bp8 = (const char*)Wf8 + (size_t)(w * 8) * 10240 + (size_t)l * 32;

    const int rot = blk % 5;
    auto kstep = [&](int ks) {
        i32x8 a[4];
#pragma unroll
        for (int j = 0; j < 4; ++j) {
            i32x4 lo = *(const i32x4*)(Afrag8 + (size_t)(((j * 5 + ks) * 2 + 0) * 1024 + l * 16));
            i32x4 hi = *(const i32x4*)(Afrag8 + (size_t)(((j * 5 + ks) * 2 + 1) * 1024 + l * 16));
            a[j][0] = lo[0]; a[j][1] = lo[1]; a[j][2] = lo[2]; a[j][3] = lo[3];
            a[j][4] = hi[0]; a[j][5] = hi[1]; a[j][6] = hi[2]; a[j][7] = hi[3];
        }
#pragma unroll
        for (int li = 0; li < 8; ++li) {
            i32x8 b = *(const i32x8*)(Bp8 + (size_t)li * 10240 + (size_t)ks * 2048);
#pragma unroll
            for (int j = 0; j < 4; ++j)
                acc[j][li] = __builtin_amdgcn_mfma_scale_f32_16x16x128_f8f6f4(
                    a[j], b, acc[j][li], 0, 0,
                    0, 0x7F7F7F7F, 0, 0x7F7F7F7F);   // scales = 1.0 (e8m0 127)
        }
    };
    for (int ks0 = rot; ks0 < 5; ++ks0) kstep(ks0);
    for (int ks0 = 0; ks0 < rot; ++ks0) kstep(ks0);

    // per-thread target tokens for the 16 owned rows
    int tg[4][4];
#pragma unroll
    for (int j = 0; j < 4; ++j)
#pragma unroll
        for (int i = 0; i < 4; ++i) {
            int r = blk * 64 + 16 * j + lhi * 4 + i; if (r > RTOT - 1) r = RTOT - 1;
            int b = r / (TT * U1); int rem = r - b * (TT * U1);
            int u = rem % U1;
            tg[j][i] = (u < UU) ? target[b * UU + u] : -1;
        }

    float se[4][4], ee[4][4], bbv[4][4];
#pragma unroll
    for (int j = 0; j < 4; ++j)
#pragma unroll
        for (int i = 0; i < 4; ++i) { se[j][i] = 0.f; ee[j][i] = NEGV; bbv[j][i] = NEGV; }

#pragma unroll
    for (int li = 0; li < 8; ++li) {
        int col = (w * 8 + li) * 16 + lrow;
        float bv = bo[col];
#pragma unroll
        for (int j = 0; j < 4; ++j)
#pragma unroll
            for (int i = 0; i < 4; ++i) {
                float x = acc[j][li][i] * 0.0625f + bv;   // undo x16 W scale
                se[j][i] += __expf(x);
                if (col == tg[j][i]) ee[j][i] = x;
            }
    }
    // blank col 1023 lives only at w==7, li==7, lrow==15 (uniform guard)
    if (w == 7) {
        float bv = bo[1023];
#pragma unroll
        for (int j = 0; j < 4; ++j)
#pragma unroll
            for (int i = 0; i < 4; ++i) {
                float x = acc[j][7][i] * 0.0625f + bv;
                if (lrow == 15) bbv[j][i] = x;
            }
    }
#pragma unroll
    for (int d = 1; d < 16; d <<= 1)
#pragma unroll
        for (int j = 0; j < 4; ++j)
#pragma unroll
            for (int i = 0; i < 4; ++i) {
                se[j][i] += __shfl_xor(se[j][i], d);
                ee[j][i] = fmaxf(ee[j][i], __shfl_xor(ee[j][i], d));
                bbv[j][i] = fmaxf(bbv[j][i], __shfl_xor(bbv[j][i], d));
            }

    // Afrag8 dead; overlay cross-wave reduction arrays [64][8].
    __syncthreads();
    float (*ps)[8] = (float (*)[8])(smbuf);
    float (*pe)[8] = (float (*)[8])(smbuf + 2048);
    float (*pb)[8] = (float (*)[8])(smbuf + 4096);
    if (lrow == 0) {
#pragma unroll
        for (int j = 0; j < 4; ++j)
#pragma unroll
            for (int i = 0; i < 4; ++i) {
                int r = 16 * j + lhi * 4 + i;
                ps[r][w] = se[j][i]; pe[r][w] = ee[j][i]; pb[r][w] = bbv[j][i];
            }
    }
    __syncthreads();
    if (tid < 64) {
        float s = 0.f, e = NEGV, bq = NEGV;
#pragma unroll
        for (int w0 = 0; w0 < 8; ++w0) {
            s += ps[tid][w0];
            e = fmaxf(e, pe[tid][w0]);
            bq = fmaxf(bq, pb[tid][w0]);
        }
        float lse = __logf(s);
        int gid = blk * 64 + tid;
        if (gid < RTOT) {
            blank_buf[gid] = bq - lse;
            emit_buf[gid]  = e - lse;
        }
    }
}

// ---------------- fused DPs + final combine (atomicAdd into out[0]) --------
__global__ __launch_bounds__(256)
void dp_fused(const float* __restrict__ blank_buf, const float* __restrict__ emit_buf,
              const float* __restrict__ ctc_logits, const float* __restrict__ ctc_lse,
              const int* __restrict__ target, const int* __restrict__ frame_len,
              const int* __restrict__ tgt_len,
              float* __restrict__ out)
{
    __shared__ __align__(16) float sm[28416];   // RNNT pk[64][217] float2
    const int bid = blockIdx.x;
    const int tid = threadIdx.x;

    if (bid < 4) {
        const int b = bid;
        float2* pk = (float2*)sm;               // [64][217]; t stored at t+8
        for (int i = tid; i < TT * U1; i += 256) {
            int t = i / U1, uu = i - t * U1;
            float bl = blank_buf[(b * TT + t) * U1 + uu];
            float em = emit_buf[(b * TT + t) * U1 + uu];
            pk[uu * 217 + t + 8] = make_float2(bl, em);
        }
        __syncthreads();
        if (tid >= 64) return;
        const int u = tid;
        const int fl = frame_len[b], tl = tgt_len[b];
        const int dh = fl - 1 + tl;             // harvest diagonal
        const bool isTL = (u == tl);
        const bool act = (u < U1);
        float A = (u == 0) ? 0.f : NEGV;
        float Asave = (dh == 0 && isTL) ? A : NEGV;
        const float2* prow = pk + u * 217;

        for (int d0 = 1; d0 <= 249; d0 += 8) {
            int tb = d0 - 1 - u;
            int tc = tb; if (tc < -8) tc = -8; if (tc > 200) tc = 200;
            float2 buf[8];
#pragma unroll
            for (int s = 0; s < 8; ++s) buf[s] = prow[tc + 8 + s];
#pragma unroll
            for (int s = 0; s < 8; ++s) {
                int d = d0 + s;
                int t_new = d - u;
                float2 be = buf[s];
                float vshare = A + be.y;
                float left = __shfl_up(vshare, 1);
                if (u == 0) left = NEGV;
                float up = (t_new >= 1) ? (A + be.x) : NEGV;
                float Anew = lae(up, left);
                bool valid = act && (t_new >= 0) && (t_new < TT);
                A = valid ? Anew : A;
                Asave = (isTL && d == dh) ? A : Asave;
            }
        }
        if (isTL && act) {
            float bl = prow[(fl - 1) + 8].x;
            atomicAdd(out, -0.25f * (Asave + bl));
        }
    } else {
        const int b = bid - 4;
        float* lpE = sm;                         // [208]
        float* lpO = sm + 208;                   // [50][209]
        for (int i = tid; i < TT; i += 256) {
            int bt = b * TT + i;
            lpE[i] = ctc_logits[(size_t)bt * VV + (VV - 1)] - ctc_lse[bt];
        }
        for (int i = tid; i < TT * UU; i += 256) {
            int t = i / UU, uu = i - t * UU;
            int bt = b * TT + t;
            lpO[uu * 209 + t] = ctc_logits[(size_t)bt * VV + target[b * UU + uu]] - ctc_lse[bt];
        }
        __syncthreads();
        if (tid >= 64) return;
        const int u = tid;
        const int fl = frame_len[b], tl = tgt_len[b];
        const bool acte = (u <= 50);
        const bool acto = (u < 50);
        bool skip = (u >= 1 && u < UU) ? (target[b * UU + u] != target[b * UU + u - 1]) : false;
        const float* orow = lpO + u * 209;
        float old_e = (u == 0) ? lpE[0] : NEGV;
        float old_o = (u == 0) ? orow[0] : NEGV;
        float Esave = (fl == 1) ? old_e : NEGV;
        float Osave = (fl == 1) ? old_o : NEGV;

        for (int t0 = 1; t0 <= 193; t0 += 8) {
            float bo8[8], be8[8];
#pragma unroll
            for (int s = 0; s < 8; ++s) { bo8[s] = orow[t0 + s]; be8[s] = lpE[t0 + s]; }
#pragma unroll
            for (int s = 0; s < 8; ++s) {
                int t = t0 + s;
                float prev_o = __shfl_up(old_o, 1);
                if (u == 0) prev_o = NEGV;
                float ne = be8[s] + lae(old_e, prev_o);
                float no = bo8[s] + lae3(old_o, old_e, skip ? prev_o : NEGV);
                old_e = acte ? ne : NEGV;
                old_o = acto ? no : NEGV;
                bool hv = (t == fl - 1) && (t < TT);
                Esave = hv ? old_e : Esave;
                Osave = hv ? old_o : Osave;
            }
        }
        float a_last = __shfl(Esave, tl);
        float a_prev = __shfl(Osave, tl - 1);
        if (u == 0) atomicAdd(out, -0.075f * lae(a_last, a_prev));
    }
}

extern "C" void kernel_launch(void* const* d_in, const int* in_sizes, int n_in,
                              void* d_out, int out_size, void* d_ws, size_t ws_size,
                              hipStream_t stream)
{
    const float* x_enc   = (const float*)d_in[0];
    const float* x_dec   = (const float*)d_in[1];
    const int*   target  = (const int*)d_in[2];
    const int*   frame_l = (const int*)d_in[3];
    const int*   tgt_l   = (const int*)d_in[4];
    const float* W_ctc   = (const float*)d_in[5];
    const float* b_ctc   = (const float*)d_in[6];
    const float* W_enc   = (const float*)d_in[7];
    const float* W_pred  = (const float*)d_in[8];
    const float* b_joint = (const float*)d_in[9];
    const float* W_out   = (const float*)d_in[10];
    const float* b_out   = (const float*)d_in[11];
    float* out = (float*)d_out;

    float* wsf        = (float*)d_ws;
    float* enc_proj   = wsf;                       // 512000
    float* pred_proj  = wsf + 512000;              // 130560
    float* ctc_logits = wsf + 642560;              // 819200
    float* ctc_lse    = wsf + 1461760;             // 832
    float* blank_buf  = wsf + 1462592;             // 40832
    float* emit_buf   = wsf + 1503424;             // 40832 (+pad to 1544272)
    unsigned* FOut8 = (unsigned*)(wsf + 1544272);  // 163840 u32 (655360 B fp8)
    bf16_t* FEnc  = (bf16_t*)(wsf + 1708112);      // 327680 bf16
    bf16_t* FPred = (bf16_t*)(wsf + 1871952);      // 409600 bf16
    bf16_t* FCtc  = (bf16_t*)(wsf + 2076752);      // 524288 bf16

    pack_bf16<<<4928, 256, 0, stream>>>(W_enc, W_pred, W_ctc, FEnc, FPred, FCtc, out);
    mfma_gemm3<<<427, 512, 0, stream>>>(x_enc, x_dec, FEnc, FPred, FCtc, b_ctc,
                                        enc_proj, pred_proj, ctc_logits, ctc_lse,
                                        W_out, FOut8);
    joint_gemm<<<NBLK, 512, 0, stream>>>(enc_proj, pred_proj, b_joint, FOut8, b_out,
                                         target, blank_buf, emit_buf);
    dp_fused<<<8, 256, 0, stream>>>(blank_buf, emit_buf, ctc_logits, ctc_lse,
                                    target, frame_l, tgt_l, out);
}

// Round 21
// 150.249 us; speedup vs baseline: 1.0434x; 1.0434x over previous
//
#include <hip/hip_runtime.h>
#include <hip/hip_bf16.h>

typedef __bf16 bf16_t;
typedef __attribute__((ext_vector_type(8))) __bf16 bf16x8;
typedef __attribute__((ext_vector_type(4))) float f32x4;
typedef __attribute__((ext_vector_type(8))) int i32x8;
typedef __attribute__((ext_vector_type(4))) int i32x4;

#define NEGV (-1e30f)

// Problem constants
#define BB 4
#define TT 200
#define UU 50
#define U1 51
#define VV 1024
#define DD 512
#define HH 640
#define RTOT (BB*TT*U1)      // 40800
#define NBLK 638
#define SS 101

__device__ __forceinline__ float lae(float a, float b) {
    float mx = fmaxf(a, b);
    return mx + __logf(__expf(a - mx) + __expf(b - mx));
}
__device__ __forceinline__ float lae3(float a, float b, float c) {
    float mx = fmaxf(fmaxf(a, b), c);
    return mx + __logf(__expf(a - mx) + __expf(b - mx) + __expf(c - mx));
}
// cheap tanh for the fp8 build: exp + hw-rcp (1ulp, irrelevant at fp8)
__device__ __forceinline__ float tanh_rcp(float x) {
    x = fminf(fmaxf(x, -10.f), 10.f);
    float ex = __expf(2.f * x);
    float r = __builtin_amdgcn_rcpf(ex + 1.f);
    return (ex - 1.f) * r;
}

// ---------------- pack fp32 (K x N) weight into bf16 MFMA B-fragment order.
__device__ __forceinline__ void pack_seg(const float* __restrict__ W, bf16_t* __restrict__ Wf,
                                         int e, int K32, int N)
{
    int j  = e & 7;
    int l  = (e >> 3) & 63;
    int kk = (e >> 9) % K32;
    int nt = e / (K32 * 512);
    int v = nt * 16 + (l & 15);
    int k = kk * 32 + ((l >> 4) << 2) + (j & 3) + ((j >> 2) << 4);
    Wf[e] = (bf16_t)W[(size_t)k * N + v];
}

// ---- pack W_out into fp8 e4m3 (scaled x16) for the MX K=128 MFMA.
// Layout: [nt(64)][ks(5)][l(64)][32B]; byte m of lane l holds
// k = ks*128 + (l>>4)*32 + m, col v = nt*16 + (l&15).  (A shares k-map.)
__device__ __forceinline__ void pack_out8_mx(const float* __restrict__ W, unsigned* __restrict__ Wf8,
                                             int e32)
{
    int w4   = e32 & 7;          // word within 32B
    int l    = (e32 >> 3) & 63;
    int ksnt = e32 >> 9;
    int ks   = ksnt % 5;
    int nt   = ksnt / 5;
    int v = nt * 16 + (l & 15);
    int kb = ks * 128 + ((l >> 4) << 5) + w4 * 4;
    float f[4];
#pragma unroll
    for (int t = 0; t < 4; ++t) f[t] = W[(size_t)(kb + t) * VV + v] * 16.f;
    unsigned r = __builtin_amdgcn_cvt_pk_fp8_f32(f[0], f[1], 0, false);
    r = __builtin_amdgcn_cvt_pk_fp8_f32(f[2], f[3], r, true);
    Wf8[e32] = r;
}

// bf16 packs only (FOut8 rides in the gemm3 launch); also zeroes out[0]
__global__ void pack_bf16(const float* __restrict__ Wenc, const float* __restrict__ Wpred,
                          const float* __restrict__ Wctc,
                          bf16_t* __restrict__ FEnc, bf16_t* __restrict__ FPred,
                          bf16_t* __restrict__ FCtc, float* __restrict__ out)
{
    if (blockIdx.x == 0 && threadIdx.x == 0) out[0] = 0.f;
    int e = blockIdx.x * 256 + threadIdx.x;
    if (e < 327680) { pack_seg(Wenc, FEnc, e, 16, 640); return; }
    e -= 327680;
    if (e < 409600) { pack_seg(Wpred, FPred, e, 20, 640); return; }
    e -= 409600;
    pack_seg(Wctc, FCtc, e, 16, 1024);
}

// ---------------- generic bf16 MFMA GEMM (small gemms) ---------------------
template<int K32, int L, bool LSE, int J>
__device__ void gemm_dev(const float* __restrict__ A, int M, int rowbase, int K,
                         const bf16_t* __restrict__ Wf, const float* __restrict__ bias,
                         float* __restrict__ C, float* __restrict__ lse_out, int N,
                         bf16_t* Atile, float (*ps)[8])
{
    const int tid = threadIdx.x;
#pragma unroll
    for (int it = 0; it < J * K32 / 8; ++it) {
        int fi = it * 512 + tid;
        int l = fi & 63, jk = fi >> 6;
        int j = jk / K32, kk = jk - j * K32;
        int row = rowbase + j * 16 + (l & 15);
        if (row > M - 1) row = M - 1;
        int c0 = kk * 32 + ((l >> 4) << 2);
        const float4 a0 = *(const float4*)&A[(size_t)row * K + c0];
        const float4 a1 = *(const float4*)&A[(size_t)row * K + c0 + 16];
        bf16x8 v;
        v[0] = (bf16_t)a0.x; v[1] = (bf16_t)a0.y; v[2] = (bf16_t)a0.z; v[3] = (bf16_t)a0.w;
        v[4] = (bf16_t)a1.x; v[5] = (bf16_t)a1.y; v[6] = (bf16_t)a1.z; v[7] = (bf16_t)a1.w;
        *(bf16x8*)&Atile[(size_t)fi * 8] = v;
    }
    __syncthreads();

    const int l = tid & 63, w = tid >> 6;
    const int lrow = l & 15, lhi = l >> 4;

    f32x4 acc[J][L];
#pragma unroll
    for (int j = 0; j < J; ++j)
#pragma unroll
        for (int li = 0; li < L; ++li) acc[j][li] = f32x4{0.f, 0.f, 0.f, 0.f};

    for (int kk = 0; kk < K32; ++kk) {
        bf16x8 a[J];
#pragma unroll
        for (int j = 0; j < J; ++j)
            a[j] = *(const bf16x8*)&Atile[(size_t)(((j * K32 + kk) * 64 + l) * 8)];
#pragma unroll
        for (int li = 0; li < L; ++li) {
            bf16x8 b = *(const bf16x8*)&Wf[(size_t)(((w * L + li) * K32 + kk) * 64 + l) * 8];
#pragma unroll
            for (int j = 0; j < J; ++j)
                acc[j][li] = __builtin_amdgcn_mfma_f32_16x16x32_bf16(a[j], b, acc[j][li], 0, 0, 0);
        }
    }

    float se[J][4];
    if (LSE) {
#pragma unroll
        for (int j = 0; j < J; ++j)
#pragma unroll
            for (int i = 0; i < 4; ++i) se[j][i] = 0.f;
    }
#pragma unroll
    for (int j = 0; j < J; ++j)
#pragma unroll
        for (int li = 0; li < L; ++li) {
            int col = (w * L + li) * 16 + lrow;
            float bv = bias ? bias[col] : 0.f;
#pragma unroll
            for (int i = 0; i < 4; ++i) {
                int grow = rowbase + 16 * j + lhi * 4 + i;
                float x = acc[j][li][i] + bv;
                if (grow < M) C[(size_t)grow * N + col] = x;
                if (LSE) se[j][i] += __expf(x);
            }
        }
    if (LSE) {
#pragma unroll
        for (int d = 1; d < 16; d <<= 1)
#pragma unroll
            for (int j = 0; j < J; ++j)
#pragma unroll
                for (int i = 0; i < 4; ++i) se[j][i] += __shfl_xor(se[j][i], d);
        if (lrow == 0) {
#pragma unroll
            for (int j = 0; j < J; ++j)
#pragma unroll
                for (int i = 0; i < 4; ++i) ps[16 * j + lhi * 4 + i][w] = se[j][i];
        }
        __syncthreads();
        if (tid < J * 16) {
            float s = 0.f;
#pragma unroll
            for (int w0 = 0; w0 < 8; ++w0) s += ps[tid][w0];
            int grow = rowbase + tid;
            if (grow < M) lse_out[grow] = __logf(s);
        }
    }
}

// blocks 0..49 enc(J=1), 50..56 pred(J=2), 57..106 ctc(J=1),
// 107..426: pack W_out -> fp8 (concurrent on the idle CUs).
__global__ __launch_bounds__(512)
void mfma_gemm3(const float* __restrict__ x_enc, const float* __restrict__ x_dec,
                const bf16_t* __restrict__ FEnc, const bf16_t* __restrict__ FPred,
                const bf16_t* __restrict__ FCtc, const float* __restrict__ b_ctc,
                float* __restrict__ enc_proj, float* __restrict__ pred_proj,
                float* __restrict__ ctc_logits, float* __restrict__ ctc_lse,
                const float* __restrict__ Wout, unsigned* __restrict__ FOut8)
{
    __shared__ bf16_t Atile[2560 * 8];   // J=2,K32=20 max: 2560 frags
    __shared__ float ps[64][8];
    int blk = blockIdx.x;
    if (blk >= 107) {
        int e = (blk - 107) * 512 + threadIdx.x;   // 163840 u32 total
        pack_out8_mx(Wout, FOut8, e);
        return;
    }
    if (blk < 50)
        gemm_dev<16, 5, false, 1>(x_enc, 800, blk * 16, 512, FEnc, nullptr, enc_proj, nullptr, 640, Atile, ps);
    else if (blk < 57)
        gemm_dev<20, 5, false, 2>(x_dec, 204, (blk - 50) * 32, 640, FPred, nullptr, pred_proj, nullptr, 640, Atile, ps);
    else
        gemm_dev<16, 8, true, 1>(x_enc, 800, (blk - 57) * 16, 512, FCtc, b_ctc, ctc_logits, ctc_lse, 1024, Atile, ps);
}

// ---------------- fused build + MX-fp8 K=128 GEMM + row-LSE + gather -------
// Build via TWO LDS buffers (no register staging across barriers -> no
// spills): P1 row-major coalesced tanh->fp8 into tile[64][656B]; P2 direct
// LDS->LDS copy into Afrag (fragment order); K-loop/epilogue = R18.
__global__ __launch_bounds__(512)
void joint_gemm(const float* __restrict__ enc,   // (800,640)
                const float* __restrict__ pred,  // (204,640)
                const float* __restrict__ bj,    // (640)
                const unsigned* __restrict__ Wf8,// packed fp8 (x16 scale)
                const float* __restrict__ bo,    // (1024)
                const int* __restrict__ target,  // (4,50)
                float* __restrict__ blank_buf, float* __restrict__ emit_buf)
{
    __shared__ __align__(16) char tile[64 * 656];    // 41984 B (P1 output)
    __shared__ __align__(16) char Afrag8[40960];     // fragment-order A
    __shared__ const float* ep[64];
    __shared__ const float* pp[64];
    const int tid = threadIdx.x;
    const int blk = blockIdx.x;

    const int l = tid & 63, w = tid >> 6;
    const int lrow = l & 15, lhi = l >> 4;

    if (tid < 64) {
        int r = blk * 64 + tid; if (r > RTOT - 1) r = RTOT - 1;
        int b = r / (TT * U1); int rem = r - b * (TT * U1);
        int t = rem / U1;      int u = rem - t * U1;
        ep[tid] = enc + (size_t)(b * TT + t) * HH;
        pp[tid] = pred + (size_t)(b * U1 + u) * HH;
    }
    __syncthreads();

    // P1: row-major coalesced compute -> tile
#pragma unroll 4
    for (int it = 0; it < 20; ++it) {
        int i = it * 512 + tid;        // 0..10239
        int row = i / 160;
        int c4 = i - row * 160;
        int c0 = c4 * 4;
        const float4 e4 = *(const float4*)&ep[row][c0];
        const float4 p4 = *(const float4*)&pp[row][c0];
        const float4 q4 = *(const float4*)&bj[c0];
        float f0 = tanh_rcp(e4.x + p4.x + q4.x);
        float f1 = tanh_rcp(e4.y + p4.y + q4.y);
        float f2 = tanh_rcp(e4.z + p4.z + q4.z);
        float f3 = tanh_rcp(e4.w + p4.w + q4.w);
        unsigned r0 = __builtin_amdgcn_cvt_pk_fp8_f32(f0, f1, 0, false);
        unsigned v = __builtin_amdgcn_cvt_pk_fp8_f32(f2, f3, r0, true);
        *(unsigned*)&tile[row * 656 + c0] = v;
    }
    __syncthreads();

    // P2: direct LDS->LDS fragment reorder (no cross-barrier registers).
#pragma unroll
    for (int it = 0; it < 5; ++it) {
        int c = it * 512 + tid;        // 0..2559
        int lA = c & 63;
        int plane = c >> 6;            // 0..39
        int h = plane & 1;
        int jks = plane >> 1;
        int ks = jks % 5;
        int j = jks / 5;
        int row = j * 16 + (lA & 15);
        int kbase = ks * 128 + ((lA >> 4) << 5) + h * 16;
        uint4 v = *(const uint4*)&tile[row * 656 + kbase];
        *(uint4*)&Afrag8[(size_t)c * 16] = v;
    }
    __syncthreads();

    f32x4 acc[4][8];
#pragma unroll
    for (int j = 0; j < 4; ++j)
#pragma unroll
        for (int li = 0; li < 8; ++li) acc[j][li] = f32x4{0.f, 0.f, 0.f, 0.f};

    const char* Bp8 = (const char*)Wf8 + (size_t)(w * 8) * 10240 + (size_t)l * 32;

    const int rot = blk % 5;
    auto kstep = [&](int ks) {
        i32x8 a[4];
#pragma unroll
        for (int j = 0; j < 4; ++j) {
            i32x4 lo = *(const i32x4*)(Afrag8 + (size_t)(((j * 5 + ks) * 2 + 0) * 1024 + l * 16));
            i32x4 hi = *(const i32x4*)(Afrag8 + (size_t)(((j * 5 + ks) * 2 + 1) * 1024 + l * 16));
            a[j][0] = lo[0]; a[j][1] = lo[1]; a[j][2] = lo[2]; a[j][3] = lo[3];
            a[j][4] = hi[0]; a[j][5] = hi[1]; a[j][6] = hi[2]; a[j][7] = hi[3];
        }
#pragma unroll
        for (int li = 0; li < 8; ++li) {
            i32x8 b = *(const i32x8*)(Bp8 + (size_t)li * 10240 + (size_t)ks * 2048);
#pragma unroll
            for (int j = 0; j < 4; ++j)
                acc[j][li] = __builtin_amdgcn_mfma_scale_f32_16x16x128_f8f6f4(
                    a[j], b, acc[j][li], 0, 0,
                    0, 0x7F7F7F7F, 0, 0x7F7F7F7F);   // scales = 1.0 (e8m0 127)
        }
    };
    for (int ks0 = rot; ks0 < 5; ++ks0) kstep(ks0);
    for (int ks0 = 0; ks0 < rot; ++ks0) kstep(ks0);

    // per-thread target tokens for the 16 owned rows
    int tg[4][4];
#pragma unroll
    for (int j = 0; j < 4; ++j)
#pragma unroll
        for (int i = 0; i < 4; ++i) {
            int r = blk * 64 + 16 * j + lhi * 4 + i; if (r > RTOT - 1) r = RTOT - 1;
            int b = r / (TT * U1); int rem = r - b * (TT * U1);
            int u = rem % U1;
            tg[j][i] = (u < UU) ? target[b * UU + u] : -1;
        }

    float se[4][4], ee[4][4], bbv[4][4];
#pragma unroll
    for (int j = 0; j < 4; ++j)
#pragma unroll
        for (int i = 0; i < 4; ++i) { se[j][i] = 0.f; ee[j][i] = NEGV; bbv[j][i] = NEGV; }

#pragma unroll
    for (int li = 0; li < 8; ++li) {
        int col = (w * 8 + li) * 16 + lrow;
        float bv = bo[col];
#pragma unroll
        for (int j = 0; j < 4; ++j)
#pragma unroll
            for (int i = 0; i < 4; ++i) {
                float x = acc[j][li][i] * 0.0625f + bv;   // undo x16 W scale
                se[j][i] += __expf(x);
                if (col == tg[j][i]) ee[j][i] = x;
            }
    }
    // blank col 1023 lives only at w==7, li==7, lrow==15 (uniform guard)
    if (w == 7) {
        float bv = bo[1023];
#pragma unroll
        for (int j = 0; j < 4; ++j)
#pragma unroll
            for (int i = 0; i < 4; ++i) {
                float x = acc[j][7][i] * 0.0625f + bv;
                if (lrow == 15) bbv[j][i] = x;
            }
    }
#pragma unroll
    for (int d = 1; d < 16; d <<= 1)
#pragma unroll
        for (int j = 0; j < 4; ++j)
#pragma unroll
            for (int i = 0; i < 4; ++i) {
                se[j][i] += __shfl_xor(se[j][i], d);
                ee[j][i] = fmaxf(ee[j][i], __shfl_xor(ee[j][i], d));
                bbv[j][i] = fmaxf(bbv[j][i], __shfl_xor(bbv[j][i], d));
            }

    // Afrag8 dead; overlay cross-wave reduction arrays [64][8].
    __syncthreads();
    float (*ps)[8] = (float (*)[8])(Afrag8);
    float (*pe)[8] = (float (*)[8])(Afrag8 + 2048);
    float (*pb)[8] = (float (*)[8])(Afrag8 + 4096);
    if (lrow == 0) {
#pragma unroll
        for (int j = 0; j < 4; ++j)
#pragma unroll
            for (int i = 0; i < 4; ++i) {
                int r = 16 * j + lhi * 4 + i;
                ps[r][w] = se[j][i]; pe[r][w] = ee[j][i]; pb[r][w] = bbv[j][i];
            }
    }
    __syncthreads();
    if (tid < 64) {
        float s = 0.f, e = NEGV, bq = NEGV;
#pragma unroll
        for (int w0 = 0; w0 < 8; ++w0) {
            s += ps[tid][w0];
            e = fmaxf(e, pe[tid][w0]);
            bq = fmaxf(bq, pb[tid][w0]);
        }
        float lse = __logf(s);
        int gid = blk * 64 + tid;
        if (gid < RTOT) {
            blank_buf[gid] = bq - lse;
            emit_buf[gid]  = e - lse;
        }
    }
}

// ---------------- fused DPs + final combine (atomicAdd into out[0]) --------
__global__ __launch_bounds__(256)
void dp_fused(const float* __restrict__ blank_buf, const float* __restrict__ emit_buf,
              const float* __restrict__ ctc_logits, const float* __restrict__ ctc_lse,
              const int* __restrict__ target, const int* __restrict__ frame_len,
              const int* __restrict__ tgt_len,
              float* __restrict__ out)
{
    __shared__ __align__(16) float sm[28416];   // RNNT pk[64][217] float2
    const int bid = blockIdx.x;
    const int tid = threadIdx.x;

    if (bid < 4) {
        const int b = bid;
        float2* pk = (float2*)sm;               // [64][217]; t stored at t+8
        for (int i = tid; i < TT * U1; i += 256) {
            int t = i / U1, uu = i - t * U1;
            float bl = blank_buf[(b * TT + t) * U1 + uu];
            float em = emit_buf[(b * TT + t) * U1 + uu];
            pk[uu * 217 + t + 8] = make_float2(bl, em);
        }
        __syncthreads();
        if (tid >= 64) return;
        const int u = tid;
        const int fl = frame_len[b], tl = tgt_len[b];
        const int dh = fl - 1 + tl;             // harvest diagonal
        const bool isTL = (u == tl);
        const bool act = (u < U1);
        float A = (u == 0) ? 0.f : NEGV;
        float Asave = (dh == 0 && isTL) ? A : NEGV;
        const float2* prow = pk + u * 217;

        for (int d0 = 1; d0 <= 249; d0 += 8) {
            int tb = d0 - 1 - u;
            int tc = tb; if (tc < -8) tc = -8; if (tc > 200) tc = 200;
            float2 buf[8];
#pragma unroll
            for (int s = 0; s < 8; ++s) buf[s] = prow[tc + 8 + s];
#pragma unroll
            for (int s = 0; s < 8; ++s) {
                int d = d0 + s;
                int t_new = d - u;
                float2 be = buf[s];
                float vshare = A + be.y;
                float left = __shfl_up(vshare, 1);
                if (u == 0) left = NEGV;
                float up = (t_new >= 1) ? (A + be.x) : NEGV;
                float Anew = lae(up, left);
                bool valid = act && (t_new >= 0) && (t_new < TT);
                A = valid ? Anew : A;
                Asave = (isTL && d == dh) ? A : Asave;
            }
        }
        if (isTL && act) {
            float bl = prow[(fl - 1) + 8].x;
            atomicAdd(out, -0.25f * (Asave + bl));
        }
    } else {
        const int b = bid - 4;
        float* lpE = sm;                         // [208]
        float* lpO = sm + 208;                   // [50][209]
        for (int i = tid; i < TT; i += 256) {
            int bt = b * TT + i;
            lpE[i] = ctc_logits[(size_t)bt * VV + (VV - 1)] - ctc_lse[bt];
        }
        for (int i = tid; i < TT * UU; i += 256) {
            int t = i / UU, uu = i - t * UU;
            int bt = b * TT + t;
            lpO[uu * 209 + t] = ctc_logits[(size_t)bt * VV + target[b * UU + uu]] - ctc_lse[bt];
        }
        __syncthreads();
        if (tid >= 64) return;
        const int u = tid;
        const int fl = frame_len[b], tl = tgt_len[b];
        const bool acte = (u <= 50);
        const bool acto = (u < 50);
        bool skip = (u >= 1 && u < UU) ? (target[b * UU + u] != target[b * UU + u - 1]) : false;
        const float* orow = lpO + u * 209;
        float old_e = (u == 0) ? lpE[0] : NEGV;
        float old_o = (u == 0) ? orow[0] : NEGV;
        float Esave = (fl == 1) ? old_e : NEGV;
        float Osave = (fl == 1) ? old_o : NEGV;

        for (int t0 = 1; t0 <= 193; t0 += 8) {
            float bo8[8], be8[8];
#pragma unroll
            for (int s = 0; s < 8; ++s) { bo8[s] = orow[t0 + s]; be8[s] = lpE[t0 + s]; }
#pragma unroll
            for (int s = 0; s < 8; ++s) {
                int t = t0 + s;
                float prev_o = __shfl_up(old_o, 1);
                if (u == 0) prev_o = NEGV;
                float ne = be8[s] + lae(old_e, prev_o);
                float no = bo8[s] + lae3(old_o, old_e, skip ? prev_o : NEGV);
                old_e = acte ? ne : NEGV;
                old_o = acto ? no : NEGV;
                bool hv = (t == fl - 1) && (t < TT);
                Esave = hv ? old_e : Esave;
                Osave = hv ? old_o : Osave;
            }
        }
        float a_last = __shfl(Esave, tl);
        float a_prev = __shfl(Osave, tl - 1);
        if (u == 0) atomicAdd(out, -0.075f * lae(a_last, a_prev));
    }
}

extern "C" void kernel_launch(void* const* d_in, const int* in_sizes, int n_in,
                              void* d_out, int out_size, void* d_ws, size_t ws_size,
                              hipStream_t stream)
{
    const float* x_enc   = (const float*)d_in[0];
    const float* x_dec   = (const float*)d_in[1];
    const int*   target  = (const int*)d_in[2];
    const int*   frame_l = (const int*)d_in[3];
    const int*   tgt_l   = (const int*)d_in[4];
    const float* W_ctc   = (const float*)d_in[5];
    const float* b_ctc   = (const float*)d_in[6];
    const float* W_enc   = (const float*)d_in[7];
    const float* W_pred  = (const float*)d_in[8];
    const float* b_joint = (const float*)d_in[9];
    const float* W_out   = (const float*)d_in[10];
    const float* b_out   = (const float*)d_in[11];
    float* out = (float*)d_out;

    float* wsf        = (float*)d_ws;
    float* enc_proj   = wsf;                       // 512000
    float* pred_proj  = wsf + 512000;              // 130560
    float* ctc_logits = wsf + 642560;              // 819200
    float* ctc_lse    = wsf + 1461760;             // 832
    float* blank_buf  = wsf + 1462592;             // 40832
    float* emit_buf   = wsf + 1503424;             // 40832 (+pad to 1544272)
    unsigned* FOut8 = (unsigned*)(wsf + 1544272);  // 163840 u32 (655360 B fp8)
    bf16_t* FEnc  = (bf16_t*)(wsf + 1708112);      // 327680 bf16
    bf16_t* FPred = (bf16_t*)(wsf + 1871952);      // 409600 bf16
    bf16_t* FCtc  = (bf16_t*)(wsf + 2076752);      // 524288 bf16

    pack_bf16<<<4928, 256, 0, stream>>>(W_enc, W_pred, W_ctc, FEnc, FPred, FCtc, out);
    mfma_gemm3<<<427, 512, 0, stream>>>(x_enc, x_dec, FEnc, FPred, FCtc, b_ctc,
                                        enc_proj, pred_proj, ctc_logits, ctc_lse,
                                        W_out, FOut8);
    joint_gemm<<<NBLK, 512, 0, stream>>>(enc_proj, pred_proj, b_joint, FOut8, b_out,
                                         target, blank_buf, emit_buf);
    dp_fused<<<8, 256, 0, stream>>>(blank_buf, emit_buf, ctc_logits, ctc_lse,
                                    target, frame_l, tgt_l, out);
}